// Round 3
// baseline (299.899 us; speedup 1.0000x reference)
//
#include <hip/hip_runtime.h>
#include <hip/hip_bf16.h>
#include <math.h>

typedef short bf16x8 __attribute__((ext_vector_type(8)));
typedef float f32x4 __attribute__((ext_vector_type(4)));
typedef unsigned short us8 __attribute__((ext_vector_type(8)));
typedef unsigned short us4 __attribute__((ext_vector_type(4)));

namespace {
constexpr int B_ = 128;
constexpr int S_ = 64;
constexpr int H_ = 1000;
constexpr int A_ = 1000;
constexpr int M_ = 500;
constexpr int V_ = 30000;
constexpr int E_ = 620;

constexpr int KP_OUT  = 2048;  // K=2000 padded
constexpr int KP_HP   = 1024;  // K=1000 padded
constexpr int KP_IH   = 2688;  // K=2620 padded
constexpr int KP_MO   = 3648;  // K=3620 padded
constexpr int KP_PRED = 512;   // K=500 padded
constexpr int LD_CAT  = 3712;  // [hidden 1000 | emb 620 | ctx 2000 | pad]
constexpr int NP_A    = 1024;
constexpr int NP_3H   = 3072;

constexpr int Z_HP = 4, Z_GI = 4, Z_GH = 2, Z_MO = 6;

__device__ __forceinline__ unsigned short f2b(float f) {
  __hip_bfloat16 h = __float2bfloat16(f);
  return *reinterpret_cast<unsigned short*>(&h);
}
__device__ __forceinline__ float b2f(unsigned short u) {
  unsigned v = ((unsigned)u) << 16;
  return __uint_as_float(v);
}
__device__ __forceinline__ float sigmoidf_(float x) {
  return 1.0f / (1.0f + __expf(-x));
}
__device__ __forceinline__ void load_lds16(const void* g, void* l) {
  auto gp = reinterpret_cast<const __attribute__((address_space(1))) char*>(
      reinterpret_cast<uintptr_t>(g));
  unsigned loff = (unsigned)(uintptr_t)l;
  auto lp = reinterpret_cast<__attribute__((address_space(3))) char*>(loff);
  __builtin_amdgcn_global_load_lds(gp, lp, 16, 0, 0);
}
}  // namespace

// ---------------------------------------------------------------------------
// cast f32 (R,K) -> bf16 (Rp,Kp) zero-padded
// ---------------------------------------------------------------------------
__global__ __launch_bounds__(256) void cast_pad(
    const float* __restrict__ src, int R, int K,
    unsigned short* __restrict__ dst, int Rp, int Kp)
{
  const long total = (long)Rp * (Kp >> 3);
  for (long i = (long)blockIdx.x * 256 + threadIdx.x; i < total;
       i += (long)gridDim.x * 256) {
    const int r = (int)(i / (Kp >> 3));
    const int c0 = (int)(i % (Kp >> 3)) * 8;
    us8 o;
    if (r < R && c0 + 8 <= K) {
      const float4 f0 = *(const float4*)(src + (size_t)r * K + c0);
      const float4 f1 = *(const float4*)(src + (size_t)r * K + c0 + 4);
      o[0] = f2b(f0.x); o[1] = f2b(f0.y); o[2] = f2b(f0.z); o[3] = f2b(f0.w);
      o[4] = f2b(f1.x); o[5] = f2b(f1.y); o[6] = f2b(f1.z); o[7] = f2b(f1.w);
    } else {
#pragma unroll
      for (int j = 0; j < 8; ++j) {
        float v = (r < R && c0 + j < K) ? src[(size_t)r * K + c0 + j] : 0.f;
        o[j] = f2b(v);
      }
    }
    *(us8*)(dst + (size_t)r * Kp + c0) = o;
  }
}

// cast f32 (R,K) -> bf16 slice of dst at col offset coff
__global__ __launch_bounds__(256) void cast_slice(
    const float* __restrict__ src, int R, int K,
    unsigned short* __restrict__ dst, int ldd, int coff)
{
  const long total = (long)R * (K >> 2);
  for (long i = (long)blockIdx.x * 256 + threadIdx.x; i < total;
       i += (long)gridDim.x * 256) {
    const int r = (int)(i / (K >> 2));
    const int c0 = (int)(i % (K >> 2)) * 4;
    const float4 f = *(const float4*)(src + (size_t)r * K + c0);
    us4 o;
    o[0] = f2b(f.x); o[1] = f2b(f.y); o[2] = f2b(f.z); o[3] = f2b(f.w);
    *(us4*)(dst + (size_t)r * ldd + coff + c0) = o;
  }
}

// zero Wmo_bf K-tail cols 3620..3647 for rows < 1000
__global__ __launch_bounds__(256) void zero_tail(unsigned short* __restrict__ dst)
{
  const int i = blockIdx.x * 256 + threadIdx.x;
  if (i < 1000 * 28) {
    const int r = i / 28, c = 3620 + i % 28;
    dst[(size_t)r * KP_MO + c] = 0;
  }
}

// ---------------------------------------------------------------------------
// Generic 128x128 MFMA GEMM (M=128 exactly), BK=64, 4 waves, swizzled LDS.
// A: bf16 via global_load_lds (pre-swizzled source).
// B: bf16 via global_load_lds, or BF32: fp32 reg-staged + cvt + swizzled
//    ds_write with (Rv, Kv) guards (fuses the weight cast into the GEMM).
// EP_PART : store acc to Cout + z*128*ldc (split-K partials, padded buffer)
// EP_STORE: Cout[r*ldc+c] = acc + bias[c], guard c < N
// ---------------------------------------------------------------------------
enum { EP_PART = 0, EP_STORE = 1 };

template <int EPI, bool BF32>
__global__ __launch_bounds__(256, 2) void gemm128(
    const unsigned short* __restrict__ Abf, int ldA,
    const unsigned short* __restrict__ Bbf, int ldB,
    const float* __restrict__ Bf32, int ldBf, int Rv, int Kv,
    float* __restrict__ Cout, int ldc, int N, int nK,
    const float* __restrict__ bias)
{
  __shared__ __align__(16) char As[16384];
  __shared__ __align__(16) char Bs[16384];

  const int t = threadIdx.x;
  const int lane = t & 63, wid = t >> 6;
  const int wm = wid >> 1, wn = wid & 1;
  const int l15 = lane & 15, l4 = lane >> 4;
  const int n0 = blockIdx.y * 128;
  const int z = blockIdx.z, Z = gridDim.z;
  const int ks = (int)((long)nK * z / Z), ke = (int)((long)nK * (z + 1) / Z);

  f32x4 acc[4][4] = {};

  for (int kst = ks; kst < ke; ++kst) {
    const int k0 = kst * 64;
    // A stage: 4 clusters, pre-swizzled source -> linear LDS
#pragma unroll
    for (int c = 0; c < 4; ++c) {
      const unsigned ou = c * 4096 + wid * 1024;
      const unsigned oo = ou + lane * 16;
      const unsigned row = oo >> 7, cb = oo & 127u;
      const unsigned scb = cb ^ ((row & 7u) << 4);
      load_lds16((const char*)Abf + ((size_t)row * ldA + k0) * 2 + scb, As + ou);
    }
    if constexpr (BF32) {
      // issue all 8 float4 loads first, then pack+write
      float4 fb[8];
#pragma unroll
      for (int p = 0; p < 4; ++p) {
        const int idx = p * 256 + t;
        const int row = idx >> 3, cb8 = idx & 7;
        const int gr = n0 + row, gk = k0 + cb8 * 8;
        if (gr < Rv && gk + 8 <= Kv) {
          fb[2 * p]     = *(const float4*)(Bf32 + (size_t)gr * ldBf + gk);
          fb[2 * p + 1] = *(const float4*)(Bf32 + (size_t)gr * ldBf + gk + 4);
        } else {
          float tmp[8];
#pragma unroll
          for (int j2 = 0; j2 < 8; ++j2)
            tmp[j2] = (gr < Rv && gk + j2 < Kv)
                          ? Bf32[(size_t)gr * ldBf + gk + j2] : 0.f;
          fb[2 * p]     = make_float4(tmp[0], tmp[1], tmp[2], tmp[3]);
          fb[2 * p + 1] = make_float4(tmp[4], tmp[5], tmp[6], tmp[7]);
        }
      }
#pragma unroll
      for (int p = 0; p < 4; ++p) {
        const int idx = p * 256 + t;
        const int row = idx >> 3, cb8 = idx & 7;
        us8 o;
        o[0] = f2b(fb[2*p].x); o[1] = f2b(fb[2*p].y);
        o[2] = f2b(fb[2*p].z); o[3] = f2b(fb[2*p].w);
        o[4] = f2b(fb[2*p+1].x); o[5] = f2b(fb[2*p+1].y);
        o[6] = f2b(fb[2*p+1].z); o[7] = f2b(fb[2*p+1].w);
        const unsigned col = (unsigned)(cb8 * 16) ^ (((unsigned)row & 7u) << 4);
        *(us8*)(Bs + (size_t)row * 128 + col) = o;
      }
    } else {
#pragma unroll
      for (int c = 0; c < 4; ++c) {
        const unsigned ou = c * 4096 + wid * 1024;
        const unsigned oo = ou + lane * 16;
        const unsigned row = oo >> 7, cb = oo & 127u;
        const unsigned scb = cb ^ ((row & 7u) << 4);
        load_lds16((const char*)Bbf + ((size_t)(n0 + row) * ldB + k0) * 2 + scb,
                   Bs + ou);
      }
    }
    __syncthreads();

#pragma unroll
    for (int kk = 0; kk < 2; ++kk) {
      bf16x8 af[4], bfr[4];
#pragma unroll
      for (int i = 0; i < 4; ++i) {
        const unsigned ra = wm * 64 + i * 16 + l15;
        const unsigned ca = (unsigned)(kk * 64 + l4 * 16) ^ ((ra & 7u) << 4);
        af[i] = *(const bf16x8*)(As + ra * 128 + ca);
        const unsigned rb = wn * 64 + i * 16 + l15;
        const unsigned cb2 = (unsigned)(kk * 64 + l4 * 16) ^ ((rb & 7u) << 4);
        bfr[i] = *(const bf16x8*)(Bs + rb * 128 + cb2);
      }
#pragma unroll
      for (int i = 0; i < 4; ++i)
#pragma unroll
        for (int j = 0; j < 4; ++j)
          acc[i][j] = __builtin_amdgcn_mfma_f32_16x16x32_bf16(af[i], bfr[j],
                                                              acc[i][j], 0, 0, 0);
    }
    __syncthreads();
  }

  if constexpr (EPI == EP_PART) {
    float* Cz = Cout + (size_t)z * 128 * ldc;
#pragma unroll
    for (int i = 0; i < 4; ++i) {
      const int r = wm * 64 + i * 16 + l4 * 4;
#pragma unroll
      for (int j = 0; j < 4; ++j) {
        const int c = n0 + wn * 64 + j * 16 + l15;
#pragma unroll
        for (int q = 0; q < 4; ++q)
          Cz[(size_t)(r + q) * ldc + c] = acc[i][j][q];
      }
    }
  } else {
#pragma unroll
    for (int i = 0; i < 4; ++i) {
      const int r = wm * 64 + i * 16 + l4 * 4;
#pragma unroll
      for (int j = 0; j < 4; ++j) {
        const int c = n0 + wn * 64 + j * 16 + l15;
        if (c < N) {
#pragma unroll
          for (int q = 0; q < 4; ++q)
            Cout[(size_t)(r + q) * ldc + c] = acc[i][j][q] + bias[c];
        }
      }
    }
  }
}

// ---------------------------------------------------------------------------
// Energy GEMM: 64x128 tile (grid 128x8 = 1024 blocks -> 4 blocks/CU).
// A = outputs_bf via global_load_lds; B = W_op fp32 fused-cast reg-staged.
// Epilogue: energy[r] += sum_c tanh(acc + b_op[c] + b_hp[c] + sum_z hp) * ve[c]
// ---------------------------------------------------------------------------
__global__ __launch_bounds__(256, 4) void energy_gemm(
    const unsigned short* __restrict__ Abf,   // 8192 x KP_OUT
    const float* __restrict__ Wop,            // 1000 x 2000 fp32
    const float* __restrict__ b_op, const float* __restrict__ b_hp,
    const float* __restrict__ hp,             // Z_HP partials of 128 x NP_A
    const float* __restrict__ ve, float* __restrict__ energy)
{
  __shared__ __align__(16) char As[8192];
  __shared__ __align__(16) char Bs[16384];
  __shared__ float red[256];

  const int t = threadIdx.x;
  const int lane = t & 63, wid = t >> 6;
  const int l15 = lane & 15, l4 = lane >> 4;
  const int m0 = blockIdx.x * 64, n0 = blockIdx.y * 128;

  f32x4 acc[4][2] = {};

  for (int k0 = 0; k0 < KP_OUT; k0 += 64) {
    // A: 2 clusters (64 rows x 128B)
#pragma unroll
    for (int c = 0; c < 2; ++c) {
      const unsigned ou = c * 4096 + wid * 1024;
      const unsigned oo = ou + lane * 16;
      const unsigned row = oo >> 7, cb = oo & 127u;
      const unsigned scb = cb ^ ((row & 7u) << 4);
      load_lds16((const char*)Abf + ((size_t)(m0 + row) * KP_OUT + k0) * 2 + scb,
                 As + ou);
    }
    // B: fp32 reg-stage, 128 rows x 64 cols
    float4 fb[8];
#pragma unroll
    for (int p = 0; p < 4; ++p) {
      const int idx = p * 256 + t;
      const int row = idx >> 3, cb8 = idx & 7;
      const int gr = n0 + row, gk = k0 + cb8 * 8;
      if (gr < A_ && gk + 8 <= 2000) {
        fb[2 * p]     = *(const float4*)(Wop + (size_t)gr * 2000 + gk);
        fb[2 * p + 1] = *(const float4*)(Wop + (size_t)gr * 2000 + gk + 4);
      } else {
        float tmp[8];
#pragma unroll
        for (int j2 = 0; j2 < 8; ++j2)
          tmp[j2] = (gr < A_ && gk + j2 < 2000)
                        ? Wop[(size_t)gr * 2000 + gk + j2] : 0.f;
        fb[2 * p]     = make_float4(tmp[0], tmp[1], tmp[2], tmp[3]);
        fb[2 * p + 1] = make_float4(tmp[4], tmp[5], tmp[6], tmp[7]);
      }
    }
#pragma unroll
    for (int p = 0; p < 4; ++p) {
      const int idx = p * 256 + t;
      const int row = idx >> 3, cb8 = idx & 7;
      us8 o;
      o[0] = f2b(fb[2*p].x); o[1] = f2b(fb[2*p].y);
      o[2] = f2b(fb[2*p].z); o[3] = f2b(fb[2*p].w);
      o[4] = f2b(fb[2*p+1].x); o[5] = f2b(fb[2*p+1].y);
      o[6] = f2b(fb[2*p+1].z); o[7] = f2b(fb[2*p+1].w);
      const unsigned col = (unsigned)(cb8 * 16) ^ (((unsigned)row & 7u) << 4);
      *(us8*)(Bs + (size_t)row * 128 + col) = o;
    }
    __syncthreads();

#pragma unroll
    for (int kk = 0; kk < 2; ++kk) {
      bf16x8 af[4], bfr[2];
#pragma unroll
      for (int i = 0; i < 4; ++i) {
        const unsigned ra = i * 16 + l15;
        const unsigned ca = (unsigned)(kk * 64 + l4 * 16) ^ ((ra & 7u) << 4);
        af[i] = *(const bf16x8*)(As + ra * 128 + ca);
      }
#pragma unroll
      for (int j = 0; j < 2; ++j) {
        const unsigned rb = wid * 32 + j * 16 + l15;
        const unsigned cb2 = (unsigned)(kk * 64 + l4 * 16) ^ ((rb & 7u) << 4);
        bfr[j] = *(const bf16x8*)(Bs + rb * 128 + cb2);
      }
#pragma unroll
      for (int i = 0; i < 4; ++i)
#pragma unroll
        for (int j = 0; j < 2; ++j)
          acc[i][j] = __builtin_amdgcn_mfma_f32_16x16x32_bf16(af[i], bfr[j],
                                                              acc[i][j], 0, 0, 0);
    }
    __syncthreads();
  }

  // epilogue
  const int bb = m0 >> 6;
  float bsum[2], vev[2];
#pragma unroll
  for (int j = 0; j < 2; ++j) {
    const int c = n0 + wid * 32 + j * 16 + l15;
    if (c < A_) {
      float s = b_op[c] + b_hp[c];
#pragma unroll
      for (int zz = 0; zz < Z_HP; ++zz)
        s += hp[(size_t)zz * B_ * NP_A + (size_t)bb * NP_A + c];
      bsum[j] = s; vev[j] = ve[c];
    } else { bsum[j] = 0.f; vev[j] = 0.f; }
  }
#pragma unroll
  for (int i = 0; i < 4; ++i) {
#pragma unroll
    for (int q = 0; q < 4; ++q) {
      float s = tanhf(acc[i][0][q] + bsum[0]) * vev[0] +
                tanhf(acc[i][1][q] + bsum[1]) * vev[1];
      s += __shfl_xor(s, 1); s += __shfl_xor(s, 2);
      s += __shfl_xor(s, 4); s += __shfl_xor(s, 8);
      if (l15 == 0) red[(i * 16 + l4 * 4 + q) * 4 + wid] = s;
    }
  }
  __syncthreads();
  if (t < 64) {
    const float s = red[t * 4] + red[t * 4 + 1] + red[t * 4 + 2] + red[t * 4 + 3];
    atomicAdd(&energy[m0 + t], s);
  }
}

// ---------------------------------------------------------------------------
// softmax + ctx (from outputs_bf) + cat3 build.  grid (B, 4)
// ---------------------------------------------------------------------------
__global__ __launch_bounds__(256) void softmax_ctx_cat(
    const float* __restrict__ energy, const unsigned short* __restrict__ outb,
    const float* __restrict__ hidden, const float* __restrict__ emb,
    const int* __restrict__ x, unsigned short* __restrict__ cat3)
{
  const int b = blockIdx.x, yq = blockIdx.y;
  const int t = threadIdx.x;
  __shared__ float attn[S_];
  __shared__ float sinv_s;

  if (t < 64) {
    const float e = energy[b * S_ + t];
    float m = e;
#pragma unroll
    for (int w = 1; w < 64; w <<= 1) m = fmaxf(m, __shfl_xor(m, w));
    const float p = __expf(e - m);
    float s = p;
#pragma unroll
    for (int w = 1; w < 64; w <<= 1) s += __shfl_xor(s, w);
    attn[t] = p;
    if (t == 0) sinv_s = 1.f / s;
  }
  __syncthreads();
  const float inv = sinv_s;
  unsigned short* catb = cat3 + (size_t)b * LD_CAT;

  // ctx: 250 chunks of 8 cols, split across yq
  {
    const int c0 = (250 * yq) / 4, c1 = (250 * (yq + 1)) / 4;
    const unsigned short* ob = outb + (size_t)b * S_ * KP_OUT;
    for (int kk = c0 + t; kk < c1; kk += 256) {
      float a[8] = {0.f, 0.f, 0.f, 0.f, 0.f, 0.f, 0.f, 0.f};
      for (int s = 0; s < S_; ++s) {
        const float w = attn[s];
        const us8 v = *(const us8*)(ob + (size_t)s * KP_OUT + kk * 8);
#pragma unroll
        for (int j = 0; j < 8; ++j) a[j] = fmaf(w, b2f(v[j]), a[j]);
      }
      us4 lo, hi;
#pragma unroll
      for (int j = 0; j < 4; ++j) { lo[j] = f2b(a[j] * inv); hi[j] = f2b(a[j+4] * inv); }
      *(us4*)(catb + 1620 + kk * 8) = lo;
      *(us4*)(catb + 1620 + kk * 8 + 4) = hi;
    }
  }
  // hidden -> cols 0..999 (250 chunks of 4)
  {
    const int c0 = (250 * yq) / 4, c1 = (250 * (yq + 1)) / 4;
    for (int kk = c0 + t; kk < c1; kk += 256) {
      const float4 f = *(const float4*)(hidden + (size_t)b * H_ + kk * 4);
      us4 v; v[0] = f2b(f.x); v[1] = f2b(f.y); v[2] = f2b(f.z); v[3] = f2b(f.w);
      *(us4*)(catb + kk * 4) = v;
    }
  }
  // emb_x -> cols 1000..1619 (155 chunks of 4)
  {
    const int xi = x[b];
    const int c0 = (155 * yq) / 4, c1 = (155 * (yq + 1)) / 4;
    for (int kk = c0 + t; kk < c1; kk += 256) {
      const float4 f = *(const float4*)(emb + (size_t)xi * E_ + kk * 4);
      us4 v; v[0] = f2b(f.x); v[1] = f2b(f.y); v[2] = f2b(f.z); v[3] = f2b(f.w);
      *(us4*)(catb + 1000 + kk * 4) = v;
    }
  }
  // zero pad cols 3620..3711 (23 chunks of 4)
  if (yq == 3) {
    for (int kk = t; kk < 23; kk += 256) {
      us4 v; v[0] = 0; v[1] = 0; v[2] = 0; v[3] = 0;
      *(us4*)(catb + 3620 + kk * 4) = v;
    }
  }
}

// ---------------------------------------------------------------------------
// GRU combine: sums gi partials (Z_GI) + gh partials (Z_GH) + biases
// ---------------------------------------------------------------------------
__global__ __launch_bounds__(256) void gru_combine(
    const float* __restrict__ gi, const float* __restrict__ gh,
    const float* __restrict__ b_ih, const float* __restrict__ b_hh,
    const float* __restrict__ hidden, float* __restrict__ hout)
{
  const int idx = blockIdx.x * 256 + threadIdx.x;
  if (idx >= B_ * H_) return;
  const int b = idx / H_, h = idx - b * H_;
  float ir = b_ih[h], iz = b_ih[H_ + h], in = b_ih[2 * H_ + h];
  float hr = b_hh[h], hz = b_hh[H_ + h], hn = b_hh[2 * H_ + h];
#pragma unroll
  for (int zz = 0; zz < Z_GI; ++zz) {
    const float* g = gi + (size_t)zz * B_ * NP_3H + (size_t)b * NP_3H;
    ir += g[h]; iz += g[H_ + h]; in += g[2 * H_ + h];
  }
#pragma unroll
  for (int zz = 0; zz < Z_GH; ++zz) {
    const float* g = gh + (size_t)zz * B_ * NP_3H + (size_t)b * NP_3H;
    hr += g[h]; hz += g[H_ + h]; hn += g[2 * H_ + h];
  }
  const float r = sigmoidf_(ir + hr);
  const float zg = sigmoidf_(iz + hz);
  const float n = tanhf(in + r * hn);
  hout[idx] = (1.f - zg) * n + zg * hidden[idx];
}

// ---------------------------------------------------------------------------
// maxout: sum mo_in partials (Z_MO) + 3 biases, pairwise max, cast bf16
// ---------------------------------------------------------------------------
__global__ __launch_bounds__(256) void maxpair_cast(
    const float* __restrict__ mo_in,
    const float* __restrict__ b_lh, const float* __restrict__ b_le,
    const float* __restrict__ b_wv, unsigned short* __restrict__ mo_bf)
{
  const int idx = blockIdx.x * 256 + threadIdx.x;
  if (idx >= B_ * KP_PRED) return;
  const int r = idx >> 9, c = idx & 511;
  unsigned short o = 0;
  if (c < M_) {
    const int j0 = 2 * c, j1 = 2 * c + 1;
    float v0 = b_lh[j0] + b_le[j0] + b_wv[j0];
    float v1 = b_lh[j1] + b_le[j1] + b_wv[j1];
#pragma unroll
    for (int zz = 0; zz < Z_MO; ++zz) {
      const float* g = mo_in + (size_t)zz * B_ * NP_A + (size_t)r * NP_A;
      v0 += g[j0]; v1 += g[j1];
    }
    o = f2b(fmaxf(v0, v1));
  }
  mo_bf[idx] = o;
}

// ---------------------------------------------------------------------------
extern "C" void kernel_launch(void* const* d_in, const int* in_sizes, int n_in,
                              void* d_out, int out_size, void* d_ws, size_t ws_size,
                              hipStream_t stream)
{
  const int*   x       = (const int*)  d_in[0];
  const float* hidden  = (const float*)d_in[1];
  const float* outputs = (const float*)d_in[2];
  const float* emb     = (const float*)d_in[3];
  const float* W_hp    = (const float*)d_in[4];
  const float* b_hp    = (const float*)d_in[5];
  const float* W_op    = (const float*)d_in[6];
  const float* b_op    = (const float*)d_in[7];
  const float* v_e     = (const float*)d_in[8];
  const float* W_ih    = (const float*)d_in[9];
  const float* W_hh    = (const float*)d_in[10];
  const float* b_ih    = (const float*)d_in[11];
  const float* b_hh    = (const float*)d_in[12];
  const float* W_wv    = (const float*)d_in[13];
  const float* b_wv    = (const float*)d_in[14];
  const float* W_lh    = (const float*)d_in[15];
  const float* b_lh    = (const float*)d_in[16];
  const float* W_le    = (const float*)d_in[17];
  const float* b_le    = (const float*)d_in[18];
  const float* W_pred  = (const float*)d_in[19];
  const float* b_pred  = (const float*)d_in[20];

  char* w = (char*)d_ws;
  auto alloc = [&](size_t bytes) {
    char* p = w; w += (bytes + 255) & ~(size_t)255; return p;
  };
  unsigned short* outputs_bf = (unsigned short*)alloc((size_t)8192 * KP_OUT * 2);
  unsigned short* Wmo_bf     = (unsigned short*)alloc((size_t)NP_A * KP_MO * 2);
  unsigned short* hidden_bf  = (unsigned short*)alloc((size_t)B_ * KP_HP * 2);
  unsigned short* cat3_bf    = (unsigned short*)alloc((size_t)B_ * LD_CAT * 2);
  unsigned short* mo_bf      = (unsigned short*)alloc((size_t)B_ * KP_PRED * 2);
  float* hp     = (float*)alloc((size_t)Z_HP * B_ * NP_A * 4);
  float* energy = (float*)alloc((size_t)B_ * S_ * 4);
  float* gi     = (float*)alloc((size_t)Z_GI * B_ * NP_3H * 4);
  float* gh     = (float*)alloc((size_t)Z_GH * B_ * NP_3H * 4);
  float* mo_in  = (float*)alloc((size_t)Z_MO * B_ * NP_A * 4);

  float* pred = (float*)d_out;
  float* hout = pred + (size_t)B_ * V_;

  hipMemsetAsync(energy, 0, (size_t)B_ * S_ * 4, stream);

  const dim3 blk(256);
  auto cg = [](long groups) {
    long b = (groups + 255) / 256; return (unsigned)(b > 8192 ? 8192 : b);
  };

  // casts
  cast_pad<<<cg((long)8192 * KP_OUT / 8), blk, 0, stream>>>(
      outputs, 8192, 2000, outputs_bf, 8192, KP_OUT);
  cast_pad<<<cg((long)B_ * KP_HP / 8), blk, 0, stream>>>(
      hidden, B_, H_, hidden_bf, B_, KP_HP);
  cast_slice<<<cg((long)A_ * H_ / 4), blk, 0, stream>>>(W_lh, A_, H_, Wmo_bf, KP_MO, 0);
  cast_slice<<<cg((long)A_ * E_ / 4), blk, 0, stream>>>(W_le, A_, E_, Wmo_bf, KP_MO, 1000);
  cast_slice<<<cg((long)A_ * 2 * H_ / 4), blk, 0, stream>>>(W_wv, A_, 2 * H_, Wmo_bf, KP_MO, 1620);
  zero_tail<<<dim3(110), blk, 0, stream>>>(Wmo_bf);

  // h_proj partials (fused W_hp cast)
  gemm128<EP_PART, true><<<dim3(1, 8, Z_HP), blk, 0, stream>>>(
      hidden_bf, KP_HP, nullptr, 0, W_hp, H_, A_, H_,
      hp, NP_A, A_, KP_HP / 64, nullptr);

  // energy (fused o_proj + W_op cast + tanh + v_e reduce)
  energy_gemm<<<dim3(128, 8), blk, 0, stream>>>(
      outputs_bf, W_op, b_op, b_hp, hp, v_e, energy);

  // softmax + ctx + cat3
  softmax_ctx_cat<<<dim3(B_, 4), blk, 0, stream>>>(
      energy, outputs_bf, hidden, emb, x, cat3_bf);

  // gi partials (fused W_ih cast)
  gemm128<EP_PART, true><<<dim3(1, 24, Z_GI), blk, 0, stream>>>(
      cat3_bf + 1000, LD_CAT, nullptr, 0, W_ih, 2620, 3 * H_, 2620,
      gi, NP_3H, 3 * H_, KP_IH / 64, nullptr);

  // gh partials (fused W_hh cast)
  gemm128<EP_PART, true><<<dim3(1, 24, Z_GH), blk, 0, stream>>>(
      hidden_bf, KP_HP, nullptr, 0, W_hh, H_, 3 * H_, H_,
      gh, NP_3H, 3 * H_, KP_HP / 64, nullptr);

  // mo_in partials (B = packed Wmo bf16)
  gemm128<EP_PART, false><<<dim3(1, 8, Z_MO), blk, 0, stream>>>(
      cat3_bf, LD_CAT, Wmo_bf, KP_MO, nullptr, 0, 0, 0,
      mo_in, NP_A, 2 * M_, KP_MO / 64, nullptr);

  // h_new
  gru_combine<<<dim3((B_ * H_ + 255) / 256), blk, 0, stream>>>(
      gi, gh, b_ih, b_hh, hidden, hout);

  // mo (maxout + biases) -> bf16
  maxpair_cast<<<dim3((B_ * KP_PRED + 255) / 256), blk, 0, stream>>>(
      mo_in, b_lh, b_le, b_wv, mo_bf);

  // prediction (fused W_pred cast)
  gemm128<EP_STORE, true><<<dim3(1, 235, 1), blk, 0, stream>>>(
      mo_bf, KP_PRED, nullptr, 0, W_pred, M_, V_, M_,
      pred, V_, V_, KP_PRED / 64, b_pred);
}

// Round 4
// 252.356 us; speedup vs baseline: 1.1884x; 1.1884x over previous
//
#include <hip/hip_runtime.h>
#include <hip/hip_bf16.h>
#include <math.h>

typedef short bf16x8 __attribute__((ext_vector_type(8)));
typedef float f32x4 __attribute__((ext_vector_type(4)));
typedef unsigned short us8 __attribute__((ext_vector_type(8)));
typedef unsigned short us4 __attribute__((ext_vector_type(4)));

namespace {
constexpr int B_ = 128;
constexpr int S_ = 64;
constexpr int H_ = 1000;
constexpr int A_ = 1000;
constexpr int M_ = 500;
constexpr int V_ = 30000;
constexpr int E_ = 620;

constexpr int KP_OUT  = 2048;  // K=2000 padded
constexpr int KP_HP   = 1024;  // K=1000 padded
constexpr int KP_IH   = 2688;  // K=2620 padded
constexpr int KP_MO   = 3648;  // K=3620 padded
constexpr int KP_PRED = 512;   // K=500 padded
constexpr int LD_CAT  = 3712;  // [hidden 1000 | emb 620 | ctx 2000 | pad]
constexpr int NP_A    = 1024;
constexpr int NP_3H   = 3072;
constexpr int OROWS   = 8192;  // B_*S_

constexpr int Z_HP = 4, Z_GI = 4, Z_GH = 2, Z_MO = 6, Z_OP = 2;

__device__ __forceinline__ unsigned short f2b(float f) {
  __hip_bfloat16 h = __float2bfloat16(f);
  return *reinterpret_cast<unsigned short*>(&h);
}
__device__ __forceinline__ float b2f(unsigned short u) {
  unsigned v = ((unsigned)u) << 16;
  return __uint_as_float(v);
}
__device__ __forceinline__ float sigmoidf_(float x) {
  return 1.0f / (1.0f + __expf(-x));
}
__device__ __forceinline__ void load_lds16(const void* g, void* l) {
  auto gp = reinterpret_cast<const __attribute__((address_space(1))) char*>(
      reinterpret_cast<uintptr_t>(g));
  unsigned loff = (unsigned)(uintptr_t)l;
  auto lp = reinterpret_cast<__attribute__((address_space(3))) char*>(loff);
  __builtin_amdgcn_global_load_lds(gp, lp, 16, 0, 0);
}
}  // namespace

// ---------------------------------------------------------------------------
// cast f32 (R,K) -> bf16 (Rp,Kp) zero-padded
// ---------------------------------------------------------------------------
__global__ __launch_bounds__(256) void cast_pad(
    const float* __restrict__ src, int R, int K,
    unsigned short* __restrict__ dst, int Rp, int Kp)
{
  const long total = (long)Rp * (Kp >> 3);
  for (long i = (long)blockIdx.x * 256 + threadIdx.x; i < total;
       i += (long)gridDim.x * 256) {
    const int r = (int)(i / (Kp >> 3));
    const int c0 = (int)(i % (Kp >> 3)) * 8;
    us8 o;
    if (r < R && c0 + 8 <= K) {
      const float4 f0 = *(const float4*)(src + (size_t)r * K + c0);
      const float4 f1 = *(const float4*)(src + (size_t)r * K + c0 + 4);
      o[0] = f2b(f0.x); o[1] = f2b(f0.y); o[2] = f2b(f0.z); o[3] = f2b(f0.w);
      o[4] = f2b(f1.x); o[5] = f2b(f1.y); o[6] = f2b(f1.z); o[7] = f2b(f1.w);
    } else {
#pragma unroll
      for (int j = 0; j < 8; ++j) {
        float v = (r < R && c0 + j < K) ? src[(size_t)r * K + c0 + j] : 0.f;
        o[j] = f2b(v);
      }
    }
    *(us8*)(dst + (size_t)r * Kp + c0) = o;
  }
}

// cast f32 (R,K) -> bf16 slice of dst at col offset coff
__global__ __launch_bounds__(256) void cast_slice(
    const float* __restrict__ src, int R, int K,
    unsigned short* __restrict__ dst, int ldd, int coff)
{
  const long total = (long)R * (K >> 2);
  for (long i = (long)blockIdx.x * 256 + threadIdx.x; i < total;
       i += (long)gridDim.x * 256) {
    const int r = (int)(i / (K >> 2));
    const int c0 = (int)(i % (K >> 2)) * 4;
    const float4 f = *(const float4*)(src + (size_t)r * K + c0);
    us4 o;
    o[0] = f2b(f.x); o[1] = f2b(f.y); o[2] = f2b(f.z); o[3] = f2b(f.w);
    *(us4*)(dst + (size_t)r * ldd + coff + c0) = o;
  }
}

// zero Wmo_bf K-tail cols 3620..3647 for rows < 1000
__global__ __launch_bounds__(256) void zero_tail(unsigned short* __restrict__ dst)
{
  const int i = blockIdx.x * 256 + threadIdx.x;
  if (i < 1000 * 28) {
    const int r = i / 28, c = 3620 + i % 28;
    dst[(size_t)r * KP_MO + c] = 0;
  }
}

// ---------------------------------------------------------------------------
// 128x128-tile MFMA GEMM, BK=64, 4 waves, swizzled LDS, m0 = blockIdx.x*128.
// A: bf16 via global_load_lds (pre-swizzled source).
// B: bf16 via global_load_lds, or BF32: fp32 reg-staged + cvt + swizzled
//    ds_write with (Rv, Kv) guards. BF32 only valid when gridDim.x == 1
//    (each B-slice staged once; see R3 post-mortem).
// EP_PART : store acc to Cout[z][m0+r][c] (split-K fp32 partials)
// EP_STORE: Cout[r*ldc+c] = acc + bias[c], guard c < N
// ---------------------------------------------------------------------------
enum { EP_PART = 0, EP_STORE = 1 };

template <int EPI, bool BF32, int WPE>
__global__ __launch_bounds__(256, WPE) void gemm128(
    const unsigned short* __restrict__ Abf, int ldA,
    const unsigned short* __restrict__ Bbf, int ldB,
    const float* __restrict__ Bf32, int ldBf, int Rv, int Kv,
    float* __restrict__ Cout, int ldc, int N, int nK,
    const float* __restrict__ bias)
{
  __shared__ __align__(16) char As[16384];
  __shared__ __align__(16) char Bs[16384];

  const int t = threadIdx.x;
  const int lane = t & 63, wid = t >> 6;
  const int wm = wid >> 1, wn = wid & 1;
  const int l15 = lane & 15, l4 = lane >> 4;
  const int m0 = blockIdx.x * 128;
  const int n0 = blockIdx.y * 128;
  const int z = blockIdx.z, Z = gridDim.z;
  const int ks = (int)((long)nK * z / Z), ke = (int)((long)nK * (z + 1) / Z);

  f32x4 acc[4][4] = {};

  for (int kst = ks; kst < ke; ++kst) {
    const int k0 = kst * 64;
    // A stage: 4 clusters, pre-swizzled source -> linear LDS
#pragma unroll
    for (int c = 0; c < 4; ++c) {
      const unsigned ou = c * 4096 + wid * 1024;
      const unsigned oo = ou + lane * 16;
      const unsigned row = oo >> 7, cb = oo & 127u;
      const unsigned scb = cb ^ ((row & 7u) << 4);
      load_lds16((const char*)Abf + ((size_t)(m0 + row) * ldA + k0) * 2 + scb,
                 As + ou);
    }
    if constexpr (BF32) {
      float4 fb[8];
#pragma unroll
      for (int p = 0; p < 4; ++p) {
        const int idx = p * 256 + t;
        const int row = idx >> 3, cb8 = idx & 7;
        const int gr = n0 + row, gk = k0 + cb8 * 8;
        if (gr < Rv && gk + 8 <= Kv) {
          fb[2 * p]     = *(const float4*)(Bf32 + (size_t)gr * ldBf + gk);
          fb[2 * p + 1] = *(const float4*)(Bf32 + (size_t)gr * ldBf + gk + 4);
        } else {
          float tmp[8];
#pragma unroll
          for (int j2 = 0; j2 < 8; ++j2)
            tmp[j2] = (gr < Rv && gk + j2 < Kv)
                          ? Bf32[(size_t)gr * ldBf + gk + j2] : 0.f;
          fb[2 * p]     = make_float4(tmp[0], tmp[1], tmp[2], tmp[3]);
          fb[2 * p + 1] = make_float4(tmp[4], tmp[5], tmp[6], tmp[7]);
        }
      }
#pragma unroll
      for (int p = 0; p < 4; ++p) {
        const int idx = p * 256 + t;
        const int row = idx >> 3, cb8 = idx & 7;
        us8 o;
        o[0] = f2b(fb[2*p].x); o[1] = f2b(fb[2*p].y);
        o[2] = f2b(fb[2*p].z); o[3] = f2b(fb[2*p].w);
        o[4] = f2b(fb[2*p+1].x); o[5] = f2b(fb[2*p+1].y);
        o[6] = f2b(fb[2*p+1].z); o[7] = f2b(fb[2*p+1].w);
        const unsigned col = (unsigned)(cb8 * 16) ^ (((unsigned)row & 7u) << 4);
        *(us8*)(Bs + (size_t)row * 128 + col) = o;
      }
    } else {
#pragma unroll
      for (int c = 0; c < 4; ++c) {
        const unsigned ou = c * 4096 + wid * 1024;
        const unsigned oo = ou + lane * 16;
        const unsigned row = oo >> 7, cb = oo & 127u;
        const unsigned scb = cb ^ ((row & 7u) << 4);
        load_lds16((const char*)Bbf + ((size_t)(n0 + row) * ldB + k0) * 2 + scb,
                   Bs + ou);
      }
    }
    __syncthreads();

#pragma unroll
    for (int kk = 0; kk < 2; ++kk) {
      bf16x8 af[4], bfr[4];
#pragma unroll
      for (int i = 0; i < 4; ++i) {
        const unsigned ra = wm * 64 + i * 16 + l15;
        const unsigned ca = (unsigned)(kk * 64 + l4 * 16) ^ ((ra & 7u) << 4);
        af[i] = *(const bf16x8*)(As + ra * 128 + ca);
        const unsigned rb = wn * 64 + i * 16 + l15;
        const unsigned cb2 = (unsigned)(kk * 64 + l4 * 16) ^ ((rb & 7u) << 4);
        bfr[i] = *(const bf16x8*)(Bs + rb * 128 + cb2);
      }
#pragma unroll
      for (int i = 0; i < 4; ++i)
#pragma unroll
        for (int j = 0; j < 4; ++j)
          acc[i][j] = __builtin_amdgcn_mfma_f32_16x16x32_bf16(af[i], bfr[j],
                                                              acc[i][j], 0, 0, 0);
    }
    __syncthreads();
  }

  if constexpr (EPI == EP_PART) {
    float* Cz = Cout + (size_t)z * ((size_t)gridDim.x << 7) * ldc;
#pragma unroll
    for (int i = 0; i < 4; ++i) {
      const int r = m0 + wm * 64 + i * 16 + l4 * 4;
#pragma unroll
      for (int j = 0; j < 4; ++j) {
        const int c = n0 + wn * 64 + j * 16 + l15;
#pragma unroll
        for (int q = 0; q < 4; ++q)
          Cz[(size_t)(r + q) * ldc + c] = acc[i][j][q];
      }
    }
  } else {
#pragma unroll
    for (int i = 0; i < 4; ++i) {
      const int r = m0 + wm * 64 + i * 16 + l4 * 4;
#pragma unroll
      for (int j = 0; j < 4; ++j) {
        const int c = n0 + wn * 64 + j * 16 + l15;
        if (c < N) {
#pragma unroll
          for (int q = 0; q < 4; ++q)
            Cout[(size_t)(r + q) * ldc + c] = acc[i][j][q] + bias[c];
        }
      }
    }
  }
}

// ---------------------------------------------------------------------------
// hpc[b][c] = b_op[c] + b_hp[c] + sum_z hp_partial[z][b][c]
// ---------------------------------------------------------------------------
__global__ __launch_bounds__(256) void hp_combine(
    const float* __restrict__ hp, const float* __restrict__ b_op,
    const float* __restrict__ b_hp, float* __restrict__ hpc)
{
  const int idx = blockIdx.x * 256 + threadIdx.x;
  if (idx >= B_ * NP_A) return;
  const int c = idx & (NP_A - 1);
  float s = (c < A_) ? (b_op[c] + b_hp[c]) : 0.f;
#pragma unroll
  for (int zz = 0; zz < Z_HP; ++zz) s += hp[(size_t)zz * B_ * NP_A + idx];
  hpc[idx] = s;
}

// ---------------------------------------------------------------------------
// energy[r] = sum_c tanh(opart0[r,c] + opart1[r,c] + hpc[b,c]) * ve[c]
// one block per row; no atomics.
// ---------------------------------------------------------------------------
__global__ __launch_bounds__(256) void energy_reduce(
    const float* __restrict__ opart, const float* __restrict__ hpc,
    const float* __restrict__ ve, float* __restrict__ energy)
{
  const int r = blockIdx.x;
  const int b = r >> 6;
  const int t = threadIdx.x;
  const float* p0 = opart + (size_t)r * NP_A;
  const float* p1 = opart + (size_t)OROWS * NP_A + (size_t)r * NP_A;
  const float* hb = hpc + (size_t)b * NP_A;
  float s = 0.f;
  for (int c = t; c < A_; c += 256)
    s += tanhf(p0[c] + p1[c] + hb[c]) * ve[c];
#pragma unroll
  for (int w = 1; w < 64; w <<= 1) s += __shfl_xor(s, w);
  __shared__ float red[4];
  if ((t & 63) == 0) red[t >> 6] = s;
  __syncthreads();
  if (t == 0) energy[r] = red[0] + red[1] + red[2] + red[3];
}

// ---------------------------------------------------------------------------
// softmax + ctx (from outputs_bf) + cat3 build.  grid (B, 4)
// ---------------------------------------------------------------------------
__global__ __launch_bounds__(256) void softmax_ctx_cat(
    const float* __restrict__ energy, const unsigned short* __restrict__ outb,
    const float* __restrict__ hidden, const float* __restrict__ emb,
    const int* __restrict__ x, unsigned short* __restrict__ cat3)
{
  const int b = blockIdx.x, yq = blockIdx.y;
  const int t = threadIdx.x;
  __shared__ float attn[S_];
  __shared__ float sinv_s;

  if (t < 64) {
    const float e = energy[b * S_ + t];
    float m = e;
#pragma unroll
    for (int w = 1; w < 64; w <<= 1) m = fmaxf(m, __shfl_xor(m, w));
    const float p = __expf(e - m);
    float s = p;
#pragma unroll
    for (int w = 1; w < 64; w <<= 1) s += __shfl_xor(s, w);
    attn[t] = p;
    if (t == 0) sinv_s = 1.f / s;
  }
  __syncthreads();
  const float inv = sinv_s;
  unsigned short* catb = cat3 + (size_t)b * LD_CAT;

  // ctx: 250 chunks of 8 cols, split across yq
  {
    const int c0 = (250 * yq) / 4, c1 = (250 * (yq + 1)) / 4;
    const unsigned short* ob = outb + (size_t)b * S_ * KP_OUT;
    for (int kk = c0 + t; kk < c1; kk += 256) {
      float a[8] = {0.f, 0.f, 0.f, 0.f, 0.f, 0.f, 0.f, 0.f};
      for (int s = 0; s < S_; ++s) {
        const float w = attn[s];
        const us8 v = *(const us8*)(ob + (size_t)s * KP_OUT + kk * 8);
#pragma unroll
        for (int j = 0; j < 8; ++j) a[j] = fmaf(w, b2f(v[j]), a[j]);
      }
      us4 lo, hi;
#pragma unroll
      for (int j = 0; j < 4; ++j) { lo[j] = f2b(a[j] * inv); hi[j] = f2b(a[j+4] * inv); }
      *(us4*)(catb + 1620 + kk * 8) = lo;
      *(us4*)(catb + 1620 + kk * 8 + 4) = hi;
    }
  }
  // hidden -> cols 0..999
  {
    const int c0 = (250 * yq) / 4, c1 = (250 * (yq + 1)) / 4;
    for (int kk = c0 + t; kk < c1; kk += 256) {
      const float4 f = *(const float4*)(hidden + (size_t)b * H_ + kk * 4);
      us4 v; v[0] = f2b(f.x); v[1] = f2b(f.y); v[2] = f2b(f.z); v[3] = f2b(f.w);
      *(us4*)(catb + kk * 4) = v;
    }
  }
  // emb_x -> cols 1000..1619
  {
    const int xi = x[b];
    const int c0 = (155 * yq) / 4, c1 = (155 * (yq + 1)) / 4;
    for (int kk = c0 + t; kk < c1; kk += 256) {
      const float4 f = *(const float4*)(emb + (size_t)xi * E_ + kk * 4);
      us4 v; v[0] = f2b(f.x); v[1] = f2b(f.y); v[2] = f2b(f.z); v[3] = f2b(f.w);
      *(us4*)(catb + 1000 + kk * 4) = v;
    }
  }
  // zero pad cols 3620..3711
  if (yq == 3) {
    for (int kk = t; kk < 23; kk += 256) {
      us4 v; v[0] = 0; v[1] = 0; v[2] = 0; v[3] = 0;
      *(us4*)(catb + 3620 + kk * 4) = v;
    }
  }
}

// ---------------------------------------------------------------------------
// GRU combine: sums gi partials (Z_GI) + gh partials (Z_GH) + biases
// ---------------------------------------------------------------------------
__global__ __launch_bounds__(256) void gru_combine(
    const float* __restrict__ gi, const float* __restrict__ gh,
    const float* __restrict__ b_ih, const float* __restrict__ b_hh,
    const float* __restrict__ hidden, float* __restrict__ hout)
{
  const int idx = blockIdx.x * 256 + threadIdx.x;
  if (idx >= B_ * H_) return;
  const int b = idx / H_, h = idx - b * H_;
  float ir = b_ih[h], iz = b_ih[H_ + h], in = b_ih[2 * H_ + h];
  float hr = b_hh[h], hz = b_hh[H_ + h], hn = b_hh[2 * H_ + h];
#pragma unroll
  for (int zz = 0; zz < Z_GI; ++zz) {
    const float* g = gi + (size_t)zz * B_ * NP_3H + (size_t)b * NP_3H;
    ir += g[h]; iz += g[H_ + h]; in += g[2 * H_ + h];
  }
#pragma unroll
  for (int zz = 0; zz < Z_GH; ++zz) {
    const float* g = gh + (size_t)zz * B_ * NP_3H + (size_t)b * NP_3H;
    hr += g[h]; hz += g[H_ + h]; hn += g[2 * H_ + h];
  }
  const float r = sigmoidf_(ir + hr);
  const float zg = sigmoidf_(iz + hz);
  const float n = tanhf(in + r * hn);
  hout[idx] = (1.f - zg) * n + zg * hidden[idx];
}

// ---------------------------------------------------------------------------
// maxout: sum mo_in partials (Z_MO) + 3 biases, pairwise max, cast bf16
// ---------------------------------------------------------------------------
__global__ __launch_bounds__(256) void maxpair_cast(
    const float* __restrict__ mo_in,
    const float* __restrict__ b_lh, const float* __restrict__ b_le,
    const float* __restrict__ b_wv, unsigned short* __restrict__ mo_bf)
{
  const int idx = blockIdx.x * 256 + threadIdx.x;
  if (idx >= B_ * KP_PRED) return;
  const int r = idx >> 9, c = idx & 511;
  unsigned short o = 0;
  if (c < M_) {
    const int j0 = 2 * c, j1 = 2 * c + 1;
    float v0 = b_lh[j0] + b_le[j0] + b_wv[j0];
    float v1 = b_lh[j1] + b_le[j1] + b_wv[j1];
#pragma unroll
    for (int zz = 0; zz < Z_MO; ++zz) {
      const float* g = mo_in + (size_t)zz * B_ * NP_A + (size_t)r * NP_A;
      v0 += g[j0]; v1 += g[j1];
    }
    o = f2b(fmaxf(v0, v1));
  }
  mo_bf[idx] = o;
}

// ---------------------------------------------------------------------------
extern "C" void kernel_launch(void* const* d_in, const int* in_sizes, int n_in,
                              void* d_out, int out_size, void* d_ws, size_t ws_size,
                              hipStream_t stream)
{
  const int*   x       = (const int*)  d_in[0];
  const float* hidden  = (const float*)d_in[1];
  const float* outputs = (const float*)d_in[2];
  const float* emb     = (const float*)d_in[3];
  const float* W_hp    = (const float*)d_in[4];
  const float* b_hp    = (const float*)d_in[5];
  const float* W_op    = (const float*)d_in[6];
  const float* b_op    = (const float*)d_in[7];
  const float* v_e     = (const float*)d_in[8];
  const float* W_ih    = (const float*)d_in[9];
  const float* W_hh    = (const float*)d_in[10];
  const float* b_ih    = (const float*)d_in[11];
  const float* b_hh    = (const float*)d_in[12];
  const float* W_wv    = (const float*)d_in[13];
  const float* b_wv    = (const float*)d_in[14];
  const float* W_lh    = (const float*)d_in[15];
  const float* b_lh    = (const float*)d_in[16];
  const float* W_le    = (const float*)d_in[17];
  const float* b_le    = (const float*)d_in[18];
  const float* W_pred  = (const float*)d_in[19];
  const float* b_pred  = (const float*)d_in[20];

  char* w = (char*)d_ws;
  auto alloc = [&](size_t bytes) {
    char* p = w; w += (bytes + 255) & ~(size_t)255; return p;
  };
  unsigned short* outputs_bf = (unsigned short*)alloc((size_t)OROWS * KP_OUT * 2);
  unsigned short* W_op_bf    = (unsigned short*)alloc((size_t)NP_A * KP_OUT * 2);
  unsigned short* Wmo_bf     = (unsigned short*)alloc((size_t)NP_A * KP_MO * 2);
  unsigned short* hidden_bf  = (unsigned short*)alloc((size_t)B_ * KP_HP * 2);
  unsigned short* cat3_bf    = (unsigned short*)alloc((size_t)B_ * LD_CAT * 2);
  unsigned short* mo_bf      = (unsigned short*)alloc((size_t)B_ * KP_PRED * 2);
  float* hp     = (float*)alloc((size_t)Z_HP * B_ * NP_A * 4);
  float* hpc    = (float*)alloc((size_t)B_ * NP_A * 4);
  float* energy = (float*)alloc((size_t)B_ * S_ * 4);
  // union region: opart (dead after energy_reduce) overlaps gi/gh/mo_in
  char* un = w;
  float* opart  = (float*)un;  // Z_OP * OROWS * NP_A fp32 = 67 MB
  float* gi     = (float*)un;                                  // Z_GI*B_*NP_3H
  float* gh     = gi + (size_t)Z_GI * B_ * NP_3H;              // Z_GH*B_*NP_3H
  float* mo_in  = gh + (size_t)Z_GH * B_ * NP_3H;              // Z_MO*B_*NP_A

  float* pred = (float*)d_out;
  float* hout = pred + (size_t)B_ * V_;

  const dim3 blk(256);
  auto cg = [](long groups) {
    long b = (groups + 255) / 256; return (unsigned)(b > 8192 ? 8192 : b);
  };

  // casts
  cast_pad<<<cg((long)OROWS * KP_OUT / 8), blk, 0, stream>>>(
      outputs, OROWS, 2000, outputs_bf, OROWS, KP_OUT);
  cast_pad<<<cg((long)NP_A * KP_OUT / 8), blk, 0, stream>>>(
      W_op, A_, 2000, W_op_bf, NP_A, KP_OUT);
  cast_pad<<<cg((long)B_ * KP_HP / 8), blk, 0, stream>>>(
      hidden, B_, H_, hidden_bf, B_, KP_HP);
  cast_slice<<<cg((long)A_ * H_ / 4), blk, 0, stream>>>(W_lh, A_, H_, Wmo_bf, KP_MO, 0);
  cast_slice<<<cg((long)A_ * E_ / 4), blk, 0, stream>>>(W_le, A_, E_, Wmo_bf, KP_MO, 1000);
  cast_slice<<<cg((long)A_ * 2 * H_ / 4), blk, 0, stream>>>(W_wv, A_, 2 * H_, Wmo_bf, KP_MO, 1620);
  zero_tail<<<dim3(110), blk, 0, stream>>>(Wmo_bf);

  // h_proj partials (fused W_hp cast; grid.x==1 so cast is read-once)
  gemm128<EP_PART, true, 2><<<dim3(1, 8, Z_HP), blk, 0, stream>>>(
      hidden_bf, KP_HP, nullptr, 0, W_hp, H_, A_, H_,
      hp, NP_A, A_, KP_HP / 64, nullptr);
  hp_combine<<<dim3(B_ * NP_A / 256), blk, 0, stream>>>(hp, b_op, b_hp, hpc);

  // o_proj partials: split-K=2, 1024 blocks (4/CU), bf16 both sides
  gemm128<EP_PART, false, 4><<<dim3(64, 8, Z_OP), blk, 0, stream>>>(
      outputs_bf, KP_OUT, W_op_bf, KP_OUT, nullptr, 0, 0, 0,
      opart, NP_A, A_, KP_OUT / 64, nullptr);

  // energy = reduce(tanh(opart0+opart1+hpc) * ve)
  energy_reduce<<<dim3(OROWS), blk, 0, stream>>>(opart, hpc, v_e, energy);

  // softmax + ctx + cat3
  softmax_ctx_cat<<<dim3(B_, 4), blk, 0, stream>>>(
      energy, outputs_bf, hidden, emb, x, cat3_bf);

  // gi partials (fused W_ih cast)   [opart dead from here; union reuse]
  gemm128<EP_PART, true, 2><<<dim3(1, 24, Z_GI), blk, 0, stream>>>(
      cat3_bf + 1000, LD_CAT, nullptr, 0, W_ih, 2620, 3 * H_, 2620,
      gi, NP_3H, 3 * H_, KP_IH / 64, nullptr);

  // gh partials (fused W_hh cast)
  gemm128<EP_PART, true, 2><<<dim3(1, 24, Z_GH), blk, 0, stream>>>(
      hidden_bf, KP_HP, nullptr, 0, W_hh, H_, 3 * H_, H_,
      gh, NP_3H, 3 * H_, KP_HP / 64, nullptr);

  // mo_in partials (B = packed Wmo bf16)
  gemm128<EP_PART, false, 2><<<dim3(1, 8, Z_MO), blk, 0, stream>>>(
      cat3_bf, LD_CAT, Wmo_bf, KP_MO, nullptr, 0, 0, 0,
      mo_in, NP_A, 2 * M_, KP_MO / 64, nullptr);

  // h_new
  gru_combine<<<dim3((B_ * H_ + 255) / 256), blk, 0, stream>>>(
      gi, gh, b_ih, b_hh, hidden, hout);

  // mo (maxout + biases) -> bf16
  maxpair_cast<<<dim3((B_ * KP_PRED + 255) / 256), blk, 0, stream>>>(
      mo_in, b_lh, b_le, b_wv, mo_bf);

  // prediction (fused W_pred cast; grid.x==1)
  gemm128<EP_STORE, true, 2><<<dim3(1, 235, 1), blk, 0, stream>>>(
      mo_bf, KP_PRED, nullptr, 0, W_pred, M_, V_, M_,
      pred, V_, V_, KP_PRED / 64, b_pred);
}

// Round 5
// 213.525 us; speedup vs baseline: 1.4045x; 1.1819x over previous
//
#include <hip/hip_runtime.h>
#include <hip/hip_bf16.h>
#include <math.h>

typedef short bf16x8 __attribute__((ext_vector_type(8)));
typedef float f32x4 __attribute__((ext_vector_type(4)));
typedef unsigned short us8 __attribute__((ext_vector_type(8)));
typedef unsigned short us4 __attribute__((ext_vector_type(4)));

namespace {
constexpr int B_ = 128;
constexpr int S_ = 64;
constexpr int H_ = 1000;
constexpr int A_ = 1000;
constexpr int M_ = 500;
constexpr int V_ = 30000;
constexpr int E_ = 620;

constexpr int KP_OUT  = 2048;  // K=2000 padded
constexpr int KP_HP   = 1024;  // K=1000 padded
constexpr int KP_MO   = 3648;  // K=3620 padded
constexpr int KP_PRED = 512;   // K=500 padded
constexpr int LD_CAT  = 3712;  // [hidden 1000 | emb 620 | ctx 2000 | pad]
constexpr int NP_A    = 1024;
constexpr int NP_3H   = 3072;
constexpr int OROWS   = 8192;  // B_*S_

constexpr int Z_HP = 4, Z_GI = 4, Z_GH = 2, Z_MO = 4, Z_OP = 2;

__device__ __forceinline__ unsigned short f2b(float f) {
  __hip_bfloat16 h = __float2bfloat16(f);
  return *reinterpret_cast<unsigned short*>(&h);
}
__device__ __forceinline__ float b2f(unsigned short u) {
  unsigned v = ((unsigned)u) << 16;
  return __uint_as_float(v);
}
__device__ __forceinline__ float sigmoidf_(float x) {
  return 1.0f / (1.0f + __expf(-x));
}
__device__ __forceinline__ void load_lds16(const void* g, void* l) {
  auto gp = reinterpret_cast<const __attribute__((address_space(1))) char*>(
      reinterpret_cast<uintptr_t>(g));
  unsigned loff = (unsigned)(uintptr_t)l;
  auto lp = reinterpret_cast<__attribute__((address_space(3))) char*>(loff);
  __builtin_amdgcn_global_load_lds(gp, lp, 16, 0, 0);
}
}  // namespace

// ---------------------------------------------------------------------------
// cast f32 (R,K) -> bf16 (Rp,Kp) zero-padded
// ---------------------------------------------------------------------------
__global__ __launch_bounds__(256) void cast_pad(
    const float* __restrict__ src, int R, int K,
    unsigned short* __restrict__ dst, int Rp, int Kp)
{
  const long total = (long)Rp * (Kp >> 3);
  for (long i = (long)blockIdx.x * 256 + threadIdx.x; i < total;
       i += (long)gridDim.x * 256) {
    const int r = (int)(i / (Kp >> 3));
    const int c0 = (int)(i % (Kp >> 3)) * 8;
    us8 o;
    if (r < R && c0 + 8 <= K) {
      const float4 f0 = *(const float4*)(src + (size_t)r * K + c0);
      const float4 f1 = *(const float4*)(src + (size_t)r * K + c0 + 4);
      o[0] = f2b(f0.x); o[1] = f2b(f0.y); o[2] = f2b(f0.z); o[3] = f2b(f0.w);
      o[4] = f2b(f1.x); o[5] = f2b(f1.y); o[6] = f2b(f1.z); o[7] = f2b(f1.w);
    } else {
#pragma unroll
      for (int j = 0; j < 8; ++j) {
        float v = (r < R && c0 + j < K) ? src[(size_t)r * K + c0 + j] : 0.f;
        o[j] = f2b(v);
      }
    }
    *(us8*)(dst + (size_t)r * Kp + c0) = o;
  }
}

// cast f32 (R,K) -> bf16 slice of dst at col offset coff
__global__ __launch_bounds__(256) void cast_slice(
    const float* __restrict__ src, int R, int K,
    unsigned short* __restrict__ dst, int ldd, int coff)
{
  const long total = (long)R * (K >> 2);
  for (long i = (long)blockIdx.x * 256 + threadIdx.x; i < total;
       i += (long)gridDim.x * 256) {
    const int r = (int)(i / (K >> 2));
    const int c0 = (int)(i % (K >> 2)) * 4;
    const float4 f = *(const float4*)(src + (size_t)r * K + c0);
    us4 o;
    o[0] = f2b(f.x); o[1] = f2b(f.y); o[2] = f2b(f.z); o[3] = f2b(f.w);
    *(us4*)(dst + (size_t)r * ldd + coff + c0) = o;
  }
}

// zero Wmo_bf K-tail cols 3620..3647 for rows < 1000
__global__ __launch_bounds__(256) void zero_tail(unsigned short* __restrict__ dst)
{
  const int i = blockIdx.x * 256 + threadIdx.x;
  if (i < 1000 * 28) {
    const int r = i / 28, c = 3620 + i % 28;
    dst[(size_t)r * KP_MO + c] = 0;
  }
}

// ---------------------------------------------------------------------------
// Streaming skinny GEMM (M=128): barrier-free, LDS-free.
// C[128,N] = A[128,K]bf16 @ B[N,K]^T, B either fp32 (in-register cvt) or bf16.
// Each wave: 64 rows x 16 cols. Block 256 thr = 4 waves = 32 cols x 128 rows.
// Split-K partials (bias==null) or final store with bias + col guard.
// Two jobs per launch (wave-uniform select by blockIdx).
// ---------------------------------------------------------------------------
struct Job {
  const unsigned short* A; int lda;
  const void* B; int ldb;
  int Rv, Kv;                 // real B rows / real K (fault + zero guards)
  float* C; int ldc;
  const float* bias;          // non-null => final store mode
  int Ncol;                   // real N (final-store col guard)
  int nK, Z, ntiles;          // K-steps of 64, split-K, N/32 tiles
  int bf16B;
};

__global__ __launch_bounds__(256) void gemm_stream(Job j0, Job j1, int n0blocks)
{
  const bool first = ((int)blockIdx.x < n0blocks);
  Job j = first ? j0 : j1;
  const int bid = first ? blockIdx.x : blockIdx.x - n0blocks;
  const int tile = bid % j.ntiles, z = bid / j.ntiles;

  const int t = threadIdx.x, lane = t & 63, wid = t >> 6;
  const int l15 = lane & 15, l4 = lane >> 4;
  const int mrow = (wid & 1) * 64;
  const int ncol = tile * 32 + (wid >> 1) * 16;
  const int ks = (int)((long)j.nK * z / j.Z);
  const int ke = (int)((long)j.nK * (z + 1) / j.Z);

  const int brow = ncol + l15;
  const bool rowok = brow < j.Rv;
  const int browc = rowok ? brow : 0;
  const bf16x8 bz = {};

  f32x4 acc[4] = {};

  for (int kst = ks; kst < ke; ++kst) {
    const int k0 = kst * 64;
    // A fragments: 8 x 16B coalesced bf16 loads (padded buffers, no guards)
    bf16x8 a[4][2];
#pragma unroll
    for (int kk = 0; kk < 2; ++kk)
#pragma unroll
      for (int mf = 0; mf < 4; ++mf)
        a[mf][kk] = *(const bf16x8*)(j.A +
            (size_t)(mrow + mf * 16 + l15) * j.lda + k0 + kk * 32 + l4 * 8);

    // B fragments
    bf16x8 b[2];
    if (j.bf16B) {
      const unsigned short* Bb = (const unsigned short*)j.B;
#pragma unroll
      for (int kk = 0; kk < 2; ++kk) {
        const bf16x8 v = *(const bf16x8*)(Bb +
            (size_t)browc * j.ldb + k0 + kk * 32 + l4 * 8);
        b[kk] = rowok ? v : bz;
      }
    } else {
      const float* Bf = (const float*)j.B;
      if (k0 + 64 <= j.Kv) {  // wave-uniform fast path
#pragma unroll
        for (int kk = 0; kk < 2; ++kk) {
          const int gk = k0 + kk * 32 + l4 * 8;
          const float4 f0 = *(const float4*)(Bf + (size_t)browc * j.ldb + gk);
          const float4 f1 = *(const float4*)(Bf + (size_t)browc * j.ldb + gk + 4);
          bf16x8 v;
          v[0] = (short)f2b(f0.x); v[1] = (short)f2b(f0.y);
          v[2] = (short)f2b(f0.z); v[3] = (short)f2b(f0.w);
          v[4] = (short)f2b(f1.x); v[5] = (short)f2b(f1.y);
          v[6] = (short)f2b(f1.z); v[7] = (short)f2b(f1.w);
          b[kk] = rowok ? v : bz;
        }
      } else {  // K-edge: elementwise guarded
#pragma unroll
        for (int kk = 0; kk < 2; ++kk) {
          const int gk = k0 + kk * 32 + l4 * 8;
          bf16x8 v = {};
          if (rowok) {
#pragma unroll
            for (int e = 0; e < 8; ++e) {
              float f = (gk + e < j.Kv) ? Bf[(size_t)brow * j.ldb + gk + e] : 0.f;
              v[e] = (short)f2b(f);
            }
          }
          b[kk] = v;
        }
      }
    }

#pragma unroll
    for (int kk = 0; kk < 2; ++kk)
#pragma unroll
      for (int mf = 0; mf < 4; ++mf)
        acc[mf] = __builtin_amdgcn_mfma_f32_16x16x32_bf16(a[mf][kk], b[kk],
                                                          acc[mf], 0, 0, 0);
  }

  if (j.bias) {  // final store with bias, col guard
    const int c = ncol + l15;
    if (c < j.Ncol) {
      const float bv = j.bias[c];
#pragma unroll
      for (int mf = 0; mf < 4; ++mf) {
        const int r = mrow + mf * 16 + l4 * 4;
#pragma unroll
        for (int q = 0; q < 4; ++q)
          j.C[(size_t)(r + q) * j.ldc + c] = acc[mf][q] + bv;
      }
    }
  } else {  // split-K partial into padded buffer
    float* Cz = j.C + (size_t)z * 128 * j.ldc;
    const int c = ncol + l15;
#pragma unroll
    for (int mf = 0; mf < 4; ++mf) {
      const int r = mrow + mf * 16 + l4 * 4;
#pragma unroll
      for (int q = 0; q < 4; ++q)
        Cz[(size_t)(r + q) * j.ldc + c] = acc[mf][q];
    }
  }
}

// ---------------------------------------------------------------------------
// o_proj GEMM: 128x128 tile, BK=64, 4 waves, swizzled LDS, bf16 both sides
// via global_load_lds. Split-K over grid.z -> fp32 partials.
// ---------------------------------------------------------------------------
__global__ __launch_bounds__(256, 4) void gemm128_part(
    const unsigned short* __restrict__ Abf, int ldA,
    const unsigned short* __restrict__ Bbf, int ldB,
    float* __restrict__ Cout, int ldc, int nK)
{
  __shared__ __align__(16) char As[16384];
  __shared__ __align__(16) char Bs[16384];

  const int t = threadIdx.x;
  const int lane = t & 63, wid = t >> 6;
  const int wm = wid >> 1, wn = wid & 1;
  const int l15 = lane & 15, l4 = lane >> 4;
  const int m0 = blockIdx.x * 128;
  const int n0 = blockIdx.y * 128;
  const int z = blockIdx.z, Z = gridDim.z;
  const int ks = (int)((long)nK * z / Z), ke = (int)((long)nK * (z + 1) / Z);

  f32x4 acc[4][4] = {};

  for (int kst = ks; kst < ke; ++kst) {
    const int k0 = kst * 64;
#pragma unroll
    for (int c = 0; c < 4; ++c) {
      const unsigned ou = c * 4096 + wid * 1024;
      const unsigned oo = ou + lane * 16;
      const unsigned row = oo >> 7, cb = oo & 127u;
      const unsigned scb = cb ^ ((row & 7u) << 4);
      load_lds16((const char*)Abf + ((size_t)(m0 + row) * ldA + k0) * 2 + scb,
                 As + ou);
    }
#pragma unroll
    for (int c = 0; c < 4; ++c) {
      const unsigned ou = c * 4096 + wid * 1024;
      const unsigned oo = ou + lane * 16;
      const unsigned row = oo >> 7, cb = oo & 127u;
      const unsigned scb = cb ^ ((row & 7u) << 4);
      load_lds16((const char*)Bbf + ((size_t)(n0 + row) * ldB + k0) * 2 + scb,
                 Bs + ou);
    }
    __syncthreads();

#pragma unroll
    for (int kk = 0; kk < 2; ++kk) {
      bf16x8 af[4], bfr[4];
#pragma unroll
      for (int i = 0; i < 4; ++i) {
        const unsigned ra = wm * 64 + i * 16 + l15;
        const unsigned ca = (unsigned)(kk * 64 + l4 * 16) ^ ((ra & 7u) << 4);
        af[i] = *(const bf16x8*)(As + ra * 128 + ca);
        const unsigned rb = wn * 64 + i * 16 + l15;
        const unsigned cb2 = (unsigned)(kk * 64 + l4 * 16) ^ ((rb & 7u) << 4);
        bfr[i] = *(const bf16x8*)(Bs + rb * 128 + cb2);
      }
#pragma unroll
      for (int i = 0; i < 4; ++i)
#pragma unroll
        for (int j = 0; j < 4; ++j)
          acc[i][j] = __builtin_amdgcn_mfma_f32_16x16x32_bf16(af[i], bfr[j],
                                                              acc[i][j], 0, 0, 0);
    }
    __syncthreads();
  }

  float* Cz = Cout + (size_t)z * ((size_t)gridDim.x << 7) * ldc;
#pragma unroll
  for (int i = 0; i < 4; ++i) {
    const int r = m0 + wm * 64 + i * 16 + l4 * 4;
#pragma unroll
    for (int j = 0; j < 4; ++j) {
      const int c = n0 + wn * 64 + j * 16 + l15;
#pragma unroll
      for (int q = 0; q < 4; ++q)
        Cz[(size_t)(r + q) * ldc + c] = acc[i][j][q];
    }
  }
}

// ---------------------------------------------------------------------------
// hpc[b][c] = b_op[c] + b_hp[c] + sum_z hp_partial[z][b][c]
// ---------------------------------------------------------------------------
__global__ __launch_bounds__(256) void hp_combine(
    const float* __restrict__ hp, const float* __restrict__ b_op,
    const float* __restrict__ b_hp, float* __restrict__ hpc)
{
  const int idx = blockIdx.x * 256 + threadIdx.x;
  if (idx >= B_ * NP_A) return;
  const int c = idx & (NP_A - 1);
  float s = (c < A_) ? (b_op[c] + b_hp[c]) : 0.f;
#pragma unroll
  for (int zz = 0; zz < Z_HP; ++zz) s += hp[(size_t)zz * B_ * NP_A + idx];
  hpc[idx] = s;
}

// ---------------------------------------------------------------------------
// energy[r] = sum_c tanh(opart0[r,c] + opart1[r,c] + hpc[b,c]) * ve[c]
// ---------------------------------------------------------------------------
__global__ __launch_bounds__(256) void energy_reduce(
    const float* __restrict__ opart, const float* __restrict__ hpc,
    const float* __restrict__ ve, float* __restrict__ energy)
{
  const int r = blockIdx.x;
  const int b = r >> 6;
  const int t = threadIdx.x;
  const float* p0 = opart + (size_t)r * NP_A;
  const float* p1 = opart + (size_t)OROWS * NP_A + (size_t)r * NP_A;
  const float* hb = hpc + (size_t)b * NP_A;
  float s = 0.f;
  for (int c = t; c < A_; c += 256)
    s += tanhf(p0[c] + p1[c] + hb[c]) * ve[c];
#pragma unroll
  for (int w = 1; w < 64; w <<= 1) s += __shfl_xor(s, w);
  __shared__ float red[4];
  if ((t & 63) == 0) red[t >> 6] = s;
  __syncthreads();
  if (t == 0) energy[r] = red[0] + red[1] + red[2] + red[3];
}

// ---------------------------------------------------------------------------
// softmax + ctx (from outputs_bf) + cat3 build.  grid (B, 4)
// ---------------------------------------------------------------------------
__global__ __launch_bounds__(256) void softmax_ctx_cat(
    const float* __restrict__ energy, const unsigned short* __restrict__ outb,
    const float* __restrict__ hidden, const float* __restrict__ emb,
    const int* __restrict__ x, unsigned short* __restrict__ cat3)
{
  const int b = blockIdx.x, yq = blockIdx.y;
  const int t = threadIdx.x;
  __shared__ float attn[S_];
  __shared__ float sinv_s;

  if (t < 64) {
    const float e = energy[b * S_ + t];
    float m = e;
#pragma unroll
    for (int w = 1; w < 64; w <<= 1) m = fmaxf(m, __shfl_xor(m, w));
    const float p = __expf(e - m);
    float s = p;
#pragma unroll
    for (int w = 1; w < 64; w <<= 1) s += __shfl_xor(s, w);
    attn[t] = p;
    if (t == 0) sinv_s = 1.f / s;
  }
  __syncthreads();
  const float inv = sinv_s;
  unsigned short* catb = cat3 + (size_t)b * LD_CAT;

  // ctx -> cols 1620..3619
  {
    const int c0 = (250 * yq) / 4, c1 = (250 * (yq + 1)) / 4;
    const unsigned short* ob = outb + (size_t)b * S_ * KP_OUT;
    for (int kk = c0 + t; kk < c1; kk += 256) {
      float a[8] = {0.f, 0.f, 0.f, 0.f, 0.f, 0.f, 0.f, 0.f};
      for (int s = 0; s < S_; ++s) {
        const float w = attn[s];
        const us8 v = *(const us8*)(ob + (size_t)s * KP_OUT + kk * 8);
#pragma unroll
        for (int j = 0; j < 8; ++j) a[j] = fmaf(w, b2f(v[j]), a[j]);
      }
      us4 lo, hi;
#pragma unroll
      for (int j = 0; j < 4; ++j) { lo[j] = f2b(a[j] * inv); hi[j] = f2b(a[j+4] * inv); }
      *(us4*)(catb + 1620 + kk * 8) = lo;
      *(us4*)(catb + 1620 + kk * 8 + 4) = hi;
    }
  }
  // hidden -> cols 0..999
  {
    const int c0 = (250 * yq) / 4, c1 = (250 * (yq + 1)) / 4;
    for (int kk = c0 + t; kk < c1; kk += 256) {
      const float4 f = *(const float4*)(hidden + (size_t)b * H_ + kk * 4);
      us4 v; v[0] = f2b(f.x); v[1] = f2b(f.y); v[2] = f2b(f.z); v[3] = f2b(f.w);
      *(us4*)(catb + kk * 4) = v;
    }
  }
  // emb_x -> cols 1000..1619
  {
    const int xi = x[b];
    const int c0 = (155 * yq) / 4, c1 = (155 * (yq + 1)) / 4;
    for (int kk = c0 + t; kk < c1; kk += 256) {
      const float4 f = *(const float4*)(emb + (size_t)xi * E_ + kk * 4);
      us4 v; v[0] = f2b(f.x); v[1] = f2b(f.y); v[2] = f2b(f.z); v[3] = f2b(f.w);
      *(us4*)(catb + 1000 + kk * 4) = v;
    }
  }
  // zero pad cols 3620..3711
  if (yq == 3) {
    for (int kk = t; kk < 23; kk += 256) {
      us4 v; v[0] = 0; v[1] = 0; v[2] = 0; v[3] = 0;
      *(us4*)(catb + 3620 + kk * 4) = v;
    }
  }
}

// ---------------------------------------------------------------------------
// GRU combine: sums gi partials (Z_GI) + gh partials (Z_GH) + biases
// ---------------------------------------------------------------------------
__global__ __launch_bounds__(256) void gru_combine(
    const float* __restrict__ gi, const float* __restrict__ gh,
    const float* __restrict__ b_ih, const float* __restrict__ b_hh,
    const float* __restrict__ hidden, float* __restrict__ hout)
{
  const int idx = blockIdx.x * 256 + threadIdx.x;
  if (idx >= B_ * H_) return;
  const int b = idx / H_, h = idx - b * H_;
  float ir = b_ih[h], iz = b_ih[H_ + h], in = b_ih[2 * H_ + h];
  float hr = b_hh[h], hz = b_hh[H_ + h], hn = b_hh[2 * H_ + h];
#pragma unroll
  for (int zz = 0; zz < Z_GI; ++zz) {
    const float* g = gi + (size_t)zz * B_ * NP_3H + (size_t)b * NP_3H;
    ir += g[h]; iz += g[H_ + h]; in += g[2 * H_ + h];
  }
#pragma unroll
  for (int zz = 0; zz < Z_GH; ++zz) {
    const float* g = gh + (size_t)zz * B_ * NP_3H + (size_t)b * NP_3H;
    hr += g[h]; hz += g[H_ + h]; hn += g[2 * H_ + h];
  }
  const float r = sigmoidf_(ir + hr);
  const float zg = sigmoidf_(iz + hz);
  const float n = tanhf(in + r * hn);
  hout[idx] = (1.f - zg) * n + zg * hidden[idx];
}

// ---------------------------------------------------------------------------
// maxout: sum mo_in partials (Z_MO) + 3 biases, pairwise max, cast bf16
// ---------------------------------------------------------------------------
__global__ __launch_bounds__(256) void maxpair_cast(
    const float* __restrict__ mo_in,
    const float* __restrict__ b_lh, const float* __restrict__ b_le,
    const float* __restrict__ b_wv, unsigned short* __restrict__ mo_bf)
{
  const int idx = blockIdx.x * 256 + threadIdx.x;
  if (idx >= B_ * KP_PRED) return;
  const int r = idx >> 9, c = idx & 511;
  unsigned short o = 0;
  if (c < M_) {
    const int j0 = 2 * c, j1 = 2 * c + 1;
    float v0 = b_lh[j0] + b_le[j0] + b_wv[j0];
    float v1 = b_lh[j1] + b_le[j1] + b_wv[j1];
#pragma unroll
    for (int zz = 0; zz < Z_MO; ++zz) {
      const float* g = mo_in + (size_t)zz * B_ * NP_A + (size_t)r * NP_A;
      v0 += g[j0]; v1 += g[j1];
    }
    o = f2b(fmaxf(v0, v1));
  }
  mo_bf[idx] = o;
}

// ---------------------------------------------------------------------------
extern "C" void kernel_launch(void* const* d_in, const int* in_sizes, int n_in,
                              void* d_out, int out_size, void* d_ws, size_t ws_size,
                              hipStream_t stream)
{
  const int*   x       = (const int*)  d_in[0];
  const float* hidden  = (const float*)d_in[1];
  const float* outputs = (const float*)d_in[2];
  const float* emb     = (const float*)d_in[3];
  const float* W_hp    = (const float*)d_in[4];
  const float* b_hp    = (const float*)d_in[5];
  const float* W_op    = (const float*)d_in[6];
  const float* b_op    = (const float*)d_in[7];
  const float* v_e     = (const float*)d_in[8];
  const float* W_ih    = (const float*)d_in[9];
  const float* W_hh    = (const float*)d_in[10];
  const float* b_ih    = (const float*)d_in[11];
  const float* b_hh    = (const float*)d_in[12];
  const float* W_wv    = (const float*)d_in[13];
  const float* b_wv    = (const float*)d_in[14];
  const float* W_lh    = (const float*)d_in[15];
  const float* b_lh    = (const float*)d_in[16];
  const float* W_le    = (const float*)d_in[17];
  const float* b_le    = (const float*)d_in[18];
  const float* W_pred  = (const float*)d_in[19];
  const float* b_pred  = (const float*)d_in[20];

  char* w = (char*)d_ws;
  auto alloc = [&](size_t bytes) {
    char* p = w; w += (bytes + 255) & ~(size_t)255; return p;
  };
  unsigned short* outputs_bf = (unsigned short*)alloc((size_t)OROWS * KP_OUT * 2);
  unsigned short* W_op_bf    = (unsigned short*)alloc((size_t)NP_A * KP_OUT * 2);
  unsigned short* Wmo_bf     = (unsigned short*)alloc((size_t)NP_A * KP_MO * 2);
  unsigned short* hidden_bf  = (unsigned short*)alloc((size_t)B_ * KP_HP * 2);
  unsigned short* cat3_bf    = (unsigned short*)alloc((size_t)B_ * LD_CAT * 2);
  unsigned short* mo_bf      = (unsigned short*)alloc((size_t)B_ * KP_PRED * 2);
  float* hp     = (float*)alloc((size_t)Z_HP * B_ * NP_A * 4);
  float* hpc    = (float*)alloc((size_t)B_ * NP_A * 4);
  float* energy = (float*)alloc((size_t)B_ * S_ * 4);
  float* gh     = (float*)alloc((size_t)Z_GH * B_ * NP_3H * 4);
  // union: opart (dead after energy_reduce) overlaps gi/mo_in
  char* un = w;
  float* opart  = (float*)un;                       // Z_OP*OROWS*NP_A fp32 = 67MB
  float* gi     = (float*)un;                       // Z_GI*B_*NP_3H
  float* mo_in  = gi + (size_t)Z_GI * B_ * NP_3H;   // Z_MO*B_*NP_A

  float* pred = (float*)d_out;
  float* hout = pred + (size_t)B_ * V_;

  const dim3 blk(256);
  auto cg = [](long groups) {
    long b = (groups + 255) / 256; return (unsigned)(b > 8192 ? 8192 : b);
  };

  // casts
  cast_pad<<<cg((long)OROWS * KP_OUT / 8), blk, 0, stream>>>(
      outputs, OROWS, 2000, outputs_bf, OROWS, KP_OUT);
  cast_pad<<<cg((long)NP_A * KP_OUT / 8), blk, 0, stream>>>(
      W_op, A_, 2000, W_op_bf, NP_A, KP_OUT);
  cast_pad<<<cg((long)B_ * KP_HP / 8), blk, 0, stream>>>(
      hidden, B_, H_, hidden_bf, B_, KP_HP);
  cast_slice<<<cg((long)A_ * H_ / 4), blk, 0, stream>>>(W_lh, A_, H_, Wmo_bf, KP_MO, 0);
  cast_slice<<<cg((long)A_ * E_ / 4), blk, 0, stream>>>(W_le, A_, E_, Wmo_bf, KP_MO, 1000);
  cast_slice<<<cg((long)A_ * 2 * H_ / 4), blk, 0, stream>>>(W_wv, A_, 2 * H_, Wmo_bf, KP_MO, 1620);
  zero_tail<<<dim3(110), blk, 0, stream>>>(Wmo_bf);

  // stream L1: hp (32 tiles x Z4 = 128 blk) + gh (96 tiles x Z2 = 192 blk)
  {
    Job jhp = { hidden_bf, KP_HP, W_hp, H_, A_, H_, hp, NP_A,
                nullptr, 0, KP_HP / 64, Z_HP, NP_A / 32, 0 };
    Job jgh = { hidden_bf, KP_HP, W_hh, H_, 3 * H_, H_, gh, NP_3H,
                nullptr, 0, KP_HP / 64, Z_GH, NP_3H / 32, 0 };
    gemm_stream<<<dim3(128 + 192), blk, 0, stream>>>(jhp, jgh, 128);
  }
  hp_combine<<<dim3(B_ * NP_A / 256), blk, 0, stream>>>(hp, b_op, b_hp, hpc);

  // o_proj partials: split-K=2, 1024 blocks, bf16 both sides
  gemm128_part<<<dim3(64, 8, Z_OP), blk, 0, stream>>>(
      outputs_bf, KP_OUT, W_op_bf, KP_OUT, opart, NP_A, KP_OUT / 64);

  // energy = reduce(tanh(opart0+opart1+hpc) * ve)
  energy_reduce<<<dim3(OROWS), blk, 0, stream>>>(opart, hpc, v_e, energy);

  // softmax + ctx + cat3
  softmax_ctx_cat<<<dim3(B_, 4), blk, 0, stream>>>(
      energy, outputs_bf, hidden, emb, x, cat3_bf);

  // stream L2: gi (96 x Z4 = 384 blk) + mo (32 x Z4 = 128 blk)
  {
    Job jgi = { cat3_bf + 1000, LD_CAT, W_ih, 2620, 3 * H_, 2620, gi, NP_3H,
                nullptr, 0, 2688 / 64, Z_GI, NP_3H / 32, 0 };
    Job jmo = { cat3_bf, LD_CAT, Wmo_bf, KP_MO, 2 * M_, KP_MO, mo_in, NP_A,
                nullptr, 0, KP_MO / 64, Z_MO, NP_A / 32, 1 };
    gemm_stream<<<dim3(384 + 128), blk, 0, stream>>>(jgi, jmo, 384);
  }

  // h_new
  gru_combine<<<dim3((B_ * H_ + 255) / 256), blk, 0, stream>>>(
      gi, gh, b_ih, b_hh, hidden, hout);

  // mo (maxout + biases) -> bf16
  maxpair_cast<<<dim3((B_ * KP_PRED + 255) / 256), blk, 0, stream>>>(
      mo_in, b_lh, b_le, b_wv, mo_bf);

  // prediction: stream, final store with bias (940 blocks)
  {
    Job jpr = { mo_bf, KP_PRED, W_pred, M_, V_, M_, pred, V_,
                b_pred, V_, KP_PRED / 64, 1, 940, 0 };
    gemm_stream<<<dim3(940), blk, 0, stream>>>(jpr, jpr, 940);
  }
}